// Round 16
// baseline (108.183 us; speedup 1.0000x reference)
//
#include <hip/hip_runtime.h>
#include <cstdint>
#include <cstddef>

#define DIMX 512
#define HDIM 32
#define NHEADS 16
#define SEQ 2048
#define BATCH 2
#define MTOT (BATCH*SEQ)   // 4096
#define WIN 64
#define QSCALE 0.17677669529663687f  // 32^-0.5

typedef __bf16 bf16x8 __attribute__((ext_vector_type(8)));
typedef float f32x4 __attribute__((ext_vector_type(4)));

__device__ __forceinline__ unsigned short f2bf(float f){
  unsigned u = __builtin_bit_cast(unsigned, f);
  u += 0x7FFFu + ((u >> 16) & 1u);          // RNE
  return (unsigned short)(u >> 16);
}
__device__ __forceinline__ float bf2f(unsigned short s){
  return __builtin_bit_cast(float, ((unsigned)s) << 16);
}
__device__ __forceinline__ unsigned pk(float a, float b){
  return (unsigned)f2bf(a) | ((unsigned)f2bf(b) << 16);
}

// async global->LDS, 16B per lane; dest is wave-uniform base + lane*16 (HW)
__device__ __forceinline__ void gl_lds16(const void* g, void* l){
  __builtin_amdgcn_global_load_lds(
      (const __attribute__((address_space(1))) unsigned*)g,
      (__attribute__((address_space(3))) unsigned*)(unsigned)(unsigned long long)l,
      16, 0, 0);
}

template<int N> __device__ __forceinline__ void vmwait(){
  if      constexpr (N == 16) asm volatile("s_waitcnt vmcnt(16)" ::: "memory");
  else if constexpr (N ==  8) asm volatile("s_waitcnt vmcnt(8)"  ::: "memory");
  else if constexpr (N ==  4) asm volatile("s_waitcnt vmcnt(4)"  ::: "memory");
  else                        asm volatile("s_waitcnt vmcnt(0)"  ::: "memory");
}

// ---------- K0: fused x->bf16 convert (blocks 0..1023) + weight transposes ----------
__global__ void k_prep(const float* __restrict__ x, unsigned short* __restrict__ xb,
                       const float* __restrict__ Wq, unsigned short* __restrict__ Wqt,
                       const float* __restrict__ Wo, unsigned short* __restrict__ Wot){
  int bx = blockIdx.x;
  if (bx < 1024){                      // cvt: 8 elems/thread
    int i = bx * 256 + threadIdx.x;
    const float4* p = (const float4*)x + (size_t)i * 2;
    float4 a = p[0], b = p[1];
    uint4 o;
    o.x = pk(a.x, a.y); o.y = pk(a.z, a.w);
    o.z = pk(b.x, b.y); o.w = pk(b.z, b.w);
    ((uint4*)xb)[i] = o;
    return;
  }
  __shared__ float tile[32][33];
  int i = bx - 1024;                   // 0..767 -> (bxx 0..47, byy 0..15)
  int bxx = i % 48, byy = i / 48;
  const float* W; unsigned short* Wt; int N, n0;
  if (bxx < 32){ W = Wq; Wt = Wqt; N = 1024; n0 = bxx * 32; }
  else         { W = Wo; Wt = Wot; N = 512;  n0 = (bxx - 32) * 32; }
  int k0 = byy * 32;
  int tx = threadIdx.x & 31, ty = threadIdx.x >> 5;   // 32x8
  #pragma unroll
  for (int r = 0; r < 32; r += 8)
    tile[ty + r][tx] = W[(size_t)(k0 + ty + r) * N + n0 + tx];
  __syncthreads();
  #pragma unroll
  for (int r = 0; r < 32; r += 8)
    Wt[(size_t)(n0 + ty + r) * 512 + k0 + tx] = f2bf(tile[tx][ty + r]);
}

// ---------- K1: QKV GEMM, 128x128, 8 waves (2x4), 3-buf depth-2 (R12-proven) ----------
__launch_bounds__(512)
__global__ void k_gemm0(const unsigned short* __restrict__ A,
                        const unsigned short* __restrict__ Bt,
                        const float* __restrict__ bias,
                        unsigned short* __restrict__ qb,
                        unsigned short* __restrict__ kb,
                        unsigned short* __restrict__ vt,
                        float* __restrict__ vsum_p)
{
  const int K = 512;
  constexpr int NWG = 256;
  __shared__ __align__(16) unsigned short lds[3][256 * 64];   // 3 x 32 KB
  int tid = threadIdx.x;
  int wid = tid >> 6, lane = tid & 63;
  int wm = wid >> 2, wn = wid & 3;       // 2 x 4 wave grid
  int lane15 = lane & 15, laneh = lane >> 4;

  int g = blockIdx.x;
  int gwi = (g & 7) * (NWG / 8) + (g >> 3);
  int bm = gwi / 8, bn = gwi % 8;

  f32x4 acc[4][2] = {};

  int srow_off = lane >> 3;           // 0..7
  int spos     = lane & 7;            // 0..7

  auto STAGE = [&](int buf, int kt){
    int k0 = kt * 64;
    #pragma unroll
    for (int c = 0; c < 4; ++c){
      int g2 = wid * 4 + c;           // 0..31: 16 A groups then 16 B groups
      if (g2 < 16){
        int r = g2 * 8 + srow_off;
        int ch = spos ^ (r & 7);
        gl_lds16(A + (size_t)(bm * 128 + r) * K + k0 + ch * 8, &lds[buf][g2 * 512]);
      } else {
        int gb = g2 - 16;
        int r = gb * 8 + srow_off;
        int ch = spos ^ (r & 7);
        gl_lds16(Bt + (size_t)(bn * 128 + r) * K + k0 + ch * 8, &lds[buf][8192 + gb * 512]);
      }
    }
  };

  auto COMPUTE = [&](int buf){
    #pragma unroll
    for (int kh = 0; kh < 2; ++kh){
      int chunk = kh * 4 + laneh;
      bf16x8 af[4], bfv[2];
      #pragma unroll
      for (int mi = 0; mi < 4; ++mi){
        int row = wm * 64 + mi * 16 + lane15;
        af[mi] = *(const bf16x8*)&lds[buf][row * 64 + (chunk ^ (row & 7)) * 8];
      }
      #pragma unroll
      for (int ni = 0; ni < 2; ++ni){
        int row = wn * 32 + ni * 16 + lane15;
        bfv[ni] = *(const bf16x8*)&lds[buf][8192 + row * 64 + (chunk ^ (row & 7)) * 8];
      }
      #pragma unroll
      for (int mi = 0; mi < 4; ++mi)
        #pragma unroll
        for (int ni = 0; ni < 2; ++ni)
          acc[mi][ni] = __builtin_amdgcn_mfma_f32_16x16x32_bf16(af[mi], bfv[ni], acc[mi][ni], 0, 0, 0);
    }
  };

  STAGE(0, 0);
  STAGE(1, 1);
  #pragma unroll
  for (int kt = 0; kt < 8; ++kt){
    if (kt < 6) STAGE((kt + 2) % 3, kt + 2);
    if (kt < 6)       vmwait<8>();
    else if (kt == 6) vmwait<4>();
    else              vmwait<0>();
    __builtin_amdgcn_s_barrier();
    __builtin_amdgcn_sched_barrier(0);
    COMPUTE(kt % 3);
    __builtin_amdgcn_s_barrier();
    __builtin_amdgcn_sched_barrier(0);
  }

  if (bn >= 4){
    // ---- V path: transpose 128x128 tile in LDS, write vt + vsum partials ----
    unsigned short (*tp)[136] = (unsigned short (*)[136])&lds[0][0];  // 34.8 KB
    #pragma unroll
    for (int mi = 0; mi < 4; ++mi)
      #pragma unroll
      for (int ni = 0; ni < 2; ++ni)
        #pragma unroll
        for (int r = 0; r < 4; ++r){
          int ml = wm * 64 + mi * 16 + laneh * 4 + r;
          int nl = wn * 32 + ni * 16 + lane15;
          tp[nl][ml] = f2bf(acc[mi][ni][r] + bias[bn * 128 + nl]);
        }
    __syncthreads();
    int nl = tid >> 2, q = tid & 3;       // nl 0..127, q covers 32 s each
    int h = (bn - 4) * 4 + (nl >> 5), d = nl & 31;
    int b = bm >> 4, sc = bm & 15;        // 128-row s-chunk within batch
    int bh = b * 16 + h;
    uint4 v4[4];
    float ssum = 0.f;
    #pragma unroll
    for (int p = 0; p < 4; ++p){
      v4[p] = *(const uint4*)&tp[nl][q * 32 + p * 8];
      const unsigned* w = (const unsigned*)&v4[p];
      #pragma unroll
      for (int j = 0; j < 4; ++j)
        ssum += bf2f((unsigned short)(w[j] & 0xffff)) + bf2f((unsigned short)(w[j] >> 16));
    }
    ssum += __shfl_xor(ssum, 1); ssum += __shfl_xor(ssum, 2);
    size_t vtoff = (size_t)(bh * HDIM + d) * SEQ + sc * 128 + q * 32;
    #pragma unroll
    for (int p = 0; p < 4; ++p) *(uint4*)(vt + vtoff + p * 8) = v4[p];
    if (q == 0) vsum_p[(sc * 32 + bh) * HDIM + d] = ssum;
  } else {
    #pragma unroll
    for (int mi = 0; mi < 4; ++mi){
      #pragma unroll
      for (int ni = 0; ni < 2; ++ni){
        #pragma unroll
        for (int r = 0; r < 4; ++r){
          int m = bm * 128 + wm * 64 + mi * 16 + laneh * 4 + r;
          int n = bn * 128 + wn * 32 + ni * 16 + lane15;
          float val = acc[mi][ni][r] + bias[n];
          int b = m >> 11, s = m & 2047;
          int h = n >> 5, d = n & 31;
          size_t idx = ((size_t)(b * 16 + h) * SEQ + s) * HDIM + d;
          float sv = val / (1.0f + __expf(-val)) * QSCALE;      // silu * scale
          float tv = 1.0f - 2.0f / (1.0f + __expf(2.0f * val)); // tanh
          qb[idx] = f2bf(sv);
          kb[idx] = f2bf(tv);
        }
      }
    }
  }
}

// ---------- K4: out-proj GEMM + residual + fused last-block LayerNorm ----------
// A = ao head-major [bh][s][32]. After the 8 bn-blocks of a bm row-group all
// commit their yb tiles (threadfence + device atomic ticket), the LAST block
// performs LN for rows [bm*64, bm*64+64) and writes fp32 out. Ticket logic is
// (ticket & 7)==7: works from ANY counter base (0xAA poison / garbage), +8 per
// call per group => deterministic, no reset, no spin.
__launch_bounds__(256)
__global__ void k_gemm1(const unsigned short* __restrict__ ao,
                        const unsigned short* __restrict__ Bt,
                        const float* __restrict__ bias,
                        const unsigned short* __restrict__ xb,
                        unsigned short* __restrict__ yb,
                        const float* __restrict__ gamma,
                        const float* __restrict__ beta,
                        float* __restrict__ out,
                        unsigned* __restrict__ cnt)
{
  const int K = 512;
  constexpr int NWG = 512;
  __shared__ __align__(16) unsigned short lds[3][128 * 64];
  __shared__ unsigned s_ticket;
  int tid = threadIdx.x;
  int wid = tid >> 6, lane = tid & 63;
  int wm = wid >> 1, wn = wid & 1;
  int lane15 = lane & 15, laneh = lane >> 4;

  int g = blockIdx.x;
  int gwi = (g & 7) * (NWG / 8) + (g >> 3);
  int bm = gwi / 8, bn = gwi % 8;

  f32x4 acc[2][2] = {};

  int srow_off = lane >> 3;
  int spos     = lane & 7;

  auto STAGE = [&](int buf, int kt){
    int k0 = kt * 64;
    #pragma unroll
    for (int c = 0; c < 2; ++c){
      int cidx = wid * 2 + c;
      int m = bm * 64 + cidx * 8 + srow_off;
      int ch = spos ^ (m & 7);          // bm*64 is 8-aligned: m&7 == rowintile&7
      int head = (kt << 1) + (ch >> 2);
      int b = m >> 11, s = m & 2047;
      gl_lds16(ao + ((size_t)(b * 16 + head) * SEQ + s) * HDIM + (ch & 3) * 8,
               &lds[buf][cidx * 512]);
    }
    #pragma unroll
    for (int c = 0; c < 2; ++c){
      int cidx = wid * 2 + c;
      int r = cidx * 8 + srow_off;
      int ch = spos ^ (r & 7);
      gl_lds16(Bt + (size_t)(bn * 64 + r) * K + k0 + ch * 8, &lds[buf][4096 + cidx * 512]);
    }
  };

  auto COMPUTE = [&](int buf){
    #pragma unroll
    for (int kh = 0; kh < 2; ++kh){
      int chunk = kh * 4 + laneh;
      bf16x8 af[2], bfv[2];
      #pragma unroll
      for (int mi = 0; mi < 2; ++mi){
        int row = wm * 32 + mi * 16 + lane15;
        af[mi] = *(const bf16x8*)&lds[buf][row * 64 + (chunk ^ (row & 7)) * 8];
      }
      #pragma unroll
      for (int ni = 0; ni < 2; ++ni){
        int row = wn * 32 + ni * 16 + lane15;
        bfv[ni] = *(const bf16x8*)&lds[buf][4096 + row * 64 + (chunk ^ (row & 7)) * 8];
      }
      #pragma unroll
      for (int mi = 0; mi < 2; ++mi)
        #pragma unroll
        for (int ni = 0; ni < 2; ++ni)
          acc[mi][ni] = __builtin_amdgcn_mfma_f32_16x16x32_bf16(af[mi], bfv[ni], acc[mi][ni], 0, 0, 0);
    }
  };

  STAGE(0, 0);
  STAGE(1, 1);
  #pragma unroll
  for (int kt = 0; kt < 8; ++kt){
    if (kt < 6) STAGE((kt + 2) % 3, kt + 2);
    if (kt < 6)       vmwait<8>();
    else if (kt == 6) vmwait<4>();
    else              vmwait<0>();
    __builtin_amdgcn_s_barrier();
    __builtin_amdgcn_sched_barrier(0);
    COMPUTE(kt % 3);
    __builtin_amdgcn_s_barrier();
    __builtin_amdgcn_sched_barrier(0);
  }

  #pragma unroll
  for (int mi = 0; mi < 2; ++mi){
    #pragma unroll
    for (int ni = 0; ni < 2; ++ni){
      #pragma unroll
      for (int r = 0; r < 4; ++r){
        int m = bm * 64 + wm * 32 + mi * 16 + laneh * 4 + r;
        int n = bn * 64 + wn * 32 + ni * 16 + lane15;
        float val = acc[mi][ni][r] + bias[n];
        size_t idx = (size_t)m * DIMX + n;
        yb[idx] = f2bf(val + bf2f(xb[idx]));
      }
    }
  }

  // ---- last-block LN for this 64-row group ----
  __threadfence();                       // release: make yb tile visible
  __syncthreads();                       // all threads' stores issued+fenced
  if (tid == 0) s_ticket = atomicAdd(&cnt[bm], 1u);
  __syncthreads();
  if ((s_ticket & 7u) == 7u){
    __threadfence();                     // acquire: see all 8 blocks' yb tiles
    float4 g0 = *(const float4*)(gamma + lane * 8);
    float4 g1 = *(const float4*)(gamma + lane * 8 + 4);
    float4 b0 = *(const float4*)(beta + lane * 8);
    float4 b1 = *(const float4*)(beta + lane * 8 + 4);
    #pragma unroll
    for (int it = 0; it < 16; ++it){
      int row = bm * 64 + wid * 16 + it;
      uint4 u = *(const uint4*)(yb + (size_t)row * DIMX + lane * 8);
      const unsigned* w = (const unsigned*)&u;
      float v[8];
      #pragma unroll
      for (int j = 0; j < 4; ++j){
        v[2*j]   = bf2f((unsigned short)(w[j] & 0xffff));
        v[2*j+1] = bf2f((unsigned short)(w[j] >> 16));
      }
      float s = 0.f, ss = 0.f;
      #pragma unroll
      for (int j = 0; j < 8; ++j){ s += v[j]; ss += v[j] * v[j]; }
      #pragma unroll
      for (int mk = 1; mk < 64; mk <<= 1){ s += __shfl_xor(s, mk); ss += __shfl_xor(ss, mk); }
      float mu = s * (1.f / DIMX);
      float var = ss * (1.f / DIMX) - mu * mu;
      float inv = rsqrtf(var + 1e-5f);
      float4 o0, o1;
      o0.x = (v[0] - mu) * inv * g0.x + b0.x; o0.y = (v[1] - mu) * inv * g0.y + b0.y;
      o0.z = (v[2] - mu) * inv * g0.z + b0.z; o0.w = (v[3] - mu) * inv * g0.w + b0.w;
      o1.x = (v[4] - mu) * inv * g1.x + b1.x; o1.y = (v[5] - mu) * inv * g1.y + b1.y;
      o1.z = (v[6] - mu) * inv * g1.z + b1.z; o1.w = (v[7] - mu) * inv * g1.w + b1.w;
      float* op = out + (size_t)row * DIMX + lane * 8;
      *(float4*)op = o0; *(float4*)(op + 4) = o1;
    }
  }
}

// ---------- K3: banded attention (e^s - 1 trick), MFMA, 9 k-tiles ----------
// q/k head-major [bh][s][32]; ao also head-major [bh][s][32] (full-line writes).
__launch_bounds__(256)
__global__ void k_attn(const unsigned short* __restrict__ qb,
                       const unsigned short* __restrict__ kb,
                       const unsigned short* __restrict__ vt,
                       const float* __restrict__ vsum_p,
                       unsigned short* __restrict__ ao)
{
  __shared__ unsigned short p_lds[4][16][40];   // per-wave P staging, padded
  int tid = threadIdx.x, wid = tid >> 6, lane = tid & 63;
  int lane15 = lane & 15, laneh = lane >> 4;
  int bh = blockIdx.y;
  int s0 = blockIdx.x * 64 + wid * 16;

  bf16x8 qf = *(const bf16x8*)(qb + ((size_t)bh * SEQ + s0 + lane15) * HDIM + laneh * 8);
  float vs0 = 0.f, vs1 = 0.f;
  #pragma unroll
  for (int c = 0; c < 16; ++c){
    vs0 += vsum_p[(c * 32 + bh) * HDIM + lane15];
    vs1 += vsum_p[(c * 32 + bh) * HDIM + 16 + lane15];
  }

  f32x4 accv[2] = {};
  float dsum[4] = {0.f, 0.f, 0.f, 0.f};
  const unsigned short* kbh = kb + (size_t)bh * SEQ * HDIM;
  const unsigned short* vth = vt + (size_t)bh * HDIM * SEQ;

  // band |i-j|<=64 with i in [s0, s0+16) touches j in [s0-64, s0+80) = 9 tiles
  for (int jt = 0; jt < 9; ++jt){
    int j0 = s0 - 64 + jt * 16;
    int jc = min(max(j0 + lane15, 0), SEQ - 1);
    bf16x8 kf = *(const bf16x8*)(kbh + (size_t)jc * HDIM + laneh * 8);
    f32x4 z = {0.f, 0.f, 0.f, 0.f};
    f32x4 sv = __builtin_amdgcn_mfma_f32_16x16x32_bf16(qf, kf, z, 0, 0, 0);
    #pragma unroll
    for (int r = 0; r < 4; ++r){
      int i = s0 + laneh * 4 + r;
      int j = j0 + lane15;
      int dj = i - j;
      bool inb = (dj <= WIN) && (dj >= -WIN) && (j >= 0) && (j < SEQ);
      float w = inb ? (__expf(sv[r]) - 1.0f) : 0.0f;
      dsum[r] += w;
      p_lds[wid][laneh * 4 + r][(jt & 1) * 16 + lane15] = f2bf(w);
    }
    if (jt & 1){
      int jc0 = j0 - 16;   // 32-wide chunk base
      bf16x8 pa = *(const bf16x8*)&p_lds[wid][lane15][laneh * 8];
      int jv = min(max(jc0 + laneh * 8, 0), SEQ - 8);
      bf16x8 v0 = *(const bf16x8*)(vth + (size_t)lane15 * SEQ + jv);
      bf16x8 v1 = *(const bf16x8*)(vth + (size_t)(16 + lane15) * SEQ + jv);
      accv[0] = __builtin_amdgcn_mfma_f32_16x16x32_bf16(pa, v0, accv[0], 0, 0, 0);
      accv[1] = __builtin_amdgcn_mfma_f32_16x16x32_bf16(pa, v1, accv[1], 0, 0, 0);
    }
  }
  // tail PV for tile 8 (cols 0..15); zero cols 16..31 first
  {
    #pragma unroll
    for (int r = 0; r < 4; ++r)
      p_lds[wid][laneh * 4 + r][16 + lane15] = 0;
    int jc0 = s0 + 64;
    bf16x8 pa = *(const bf16x8*)&p_lds[wid][lane15][laneh * 8];
    int jv = min(max(jc0 + laneh * 8, 0), SEQ - 8);
    bf16x8 v0 = *(const bf16x8*)(vth + (size_t)lane15 * SEQ + jv);
    bf16x8 v1 = *(const bf16x8*)(vth + (size_t)(16 + lane15) * SEQ + jv);
    accv[0] = __builtin_amdgcn_mfma_f32_16x16x32_bf16(pa, v0, accv[0], 0, 0, 0);
    accv[1] = __builtin_amdgcn_mfma_f32_16x16x32_bf16(pa, v1, accv[1], 0, 0, 0);
  }

  #pragma unroll
  for (int r = 0; r < 4; ++r){
    float v = dsum[r];
    v += __shfl_xor(v, 1); v += __shfl_xor(v, 2);
    v += __shfl_xor(v, 4); v += __shfl_xor(v, 8);
    dsum[r] = v;
  }
  #pragma unroll
  for (int r = 0; r < 4; ++r){
    int i = s0 + laneh * 4 + r;
    float dn = (float)SEQ + dsum[r];
    float o0 = (accv[0][r] + vs0) / dn;
    float o1 = (accv[1][r] + vs1) / dn;
    size_t base = ((size_t)bh * SEQ + i) * HDIM;   // head-major: full 64B rows
    ao[base + lane15]      = f2bf(o0);
    ao[base + 16 + lane15] = f2bf(o1);
  }
}

extern "C" void kernel_launch(void* const* d_in, const int* in_sizes, int n_in,
                              void* d_out, int out_size, void* d_ws, size_t ws_size,
                              hipStream_t stream){
  const float* x      = (const float*)d_in[0];
  const float* W_qkv  = (const float*)d_in[1];
  const float* b_qkv  = (const float*)d_in[2];
  const float* W_out  = (const float*)d_in[3];
  const float* b_out  = (const float*)d_in[4];
  const float* gamma  = (const float*)d_in[5];
  const float* beta   = (const float*)d_in[6];
  float* out = (float*)d_out;

  char* ws = (char*)d_ws;
  size_t off = 0;
  auto alloc = [&](size_t bytes){ void* p = ws + off; off += (bytes + 255) & ~(size_t)255; return p; };
  unsigned short* xb  = (unsigned short*)alloc((size_t)MTOT * DIMX * 2);
  unsigned short* wqt = (unsigned short*)alloc((size_t)1024 * 512 * 2);
  unsigned short* wot = (unsigned short*)alloc((size_t)512 * 512 * 2);
  unsigned short* qb  = (unsigned short*)alloc((size_t)MTOT * DIMX * 2);
  unsigned short* kb  = (unsigned short*)alloc((size_t)MTOT * DIMX * 2);
  unsigned short* vt  = (unsigned short*)alloc((size_t)32 * HDIM * SEQ * 2);
  float*          vsm = (float*)alloc((size_t)16 * 32 * HDIM * 4);
  unsigned short* ao  = (unsigned short*)alloc((size_t)MTOT * DIMX * 2);
  unsigned short* yb  = (unsigned short*)alloc((size_t)MTOT * DIMX * 2);
  unsigned*       cnt = (unsigned*)alloc((size_t)64 * 4);

  k_prep <<<1792, 256, 0, stream>>>(x, xb, W_qkv, wqt, W_out, wot);
  k_gemm0<<<256, 512, 0, stream>>>(xb, wqt, b_qkv, qb, kb, vt, vsm);
  k_attn <<<dim3(32, 32), 256, 0, stream>>>(qb, kb, vt, vsm, ao);
  k_gemm1<<<512, 256, 0, stream>>>(ao, wot, b_out, xb, yb, gamma, beta, out, cnt);
}

// Round 17
// 43.863 us; speedup vs baseline: 2.4664x; 2.4664x over previous
//
#include <hip/hip_runtime.h>
#include <cstdint>
#include <cstddef>

#define DIMX 512
#define HDIM 32
#define NHEADS 16
#define SEQ 2048
#define BATCH 2
#define MTOT (BATCH*SEQ)   // 4096
#define WIN 64
#define QSCALE 0.17677669529663687f  // 32^-0.5

typedef __bf16 bf16x8 __attribute__((ext_vector_type(8)));
typedef float f32x4 __attribute__((ext_vector_type(4)));

__device__ __forceinline__ unsigned short f2bf(float f){
  unsigned u = __builtin_bit_cast(unsigned, f);
  u += 0x7FFFu + ((u >> 16) & 1u);          // RNE
  return (unsigned short)(u >> 16);
}
__device__ __forceinline__ float bf2f(unsigned short s){
  return __builtin_bit_cast(float, ((unsigned)s) << 16);
}
__device__ __forceinline__ unsigned pk(float a, float b){
  return (unsigned)f2bf(a) | ((unsigned)f2bf(b) << 16);
}

// async global->LDS, 16B per lane; dest is wave-uniform base + lane*16 (HW)
__device__ __forceinline__ void gl_lds16(const void* g, void* l){
  __builtin_amdgcn_global_load_lds(
      (const __attribute__((address_space(1))) unsigned*)g,
      (__attribute__((address_space(3))) unsigned*)(unsigned)(unsigned long long)l,
      16, 0, 0);
}

template<int N> __device__ __forceinline__ void vmwait(){
  if      constexpr (N == 16) asm volatile("s_waitcnt vmcnt(16)" ::: "memory");
  else if constexpr (N ==  8) asm volatile("s_waitcnt vmcnt(8)"  ::: "memory");
  else if constexpr (N ==  4) asm volatile("s_waitcnt vmcnt(4)"  ::: "memory");
  else                        asm volatile("s_waitcnt vmcnt(0)"  ::: "memory");
}

// ---------- K0: fused x->bf16 convert (blocks 0..1023) + weight transposes ----------
__global__ void k_prep(const float* __restrict__ x, unsigned short* __restrict__ xb,
                       const float* __restrict__ Wq, unsigned short* __restrict__ Wqt,
                       const float* __restrict__ Wo, unsigned short* __restrict__ Wot){
  int bx = blockIdx.x;
  if (bx < 1024){                      // cvt: 8 elems/thread
    int i = bx * 256 + threadIdx.x;
    const float4* p = (const float4*)x + (size_t)i * 2;
    float4 a = p[0], b = p[1];
    uint4 o;
    o.x = pk(a.x, a.y); o.y = pk(a.z, a.w);
    o.z = pk(b.x, b.y); o.w = pk(b.z, b.w);
    ((uint4*)xb)[i] = o;
    return;
  }
  __shared__ float tile[32][33];
  int i = bx - 1024;                   // 0..767 -> (bxx 0..47, byy 0..15)
  int bxx = i % 48, byy = i / 48;
  const float* W; unsigned short* Wt; int N, n0;
  if (bxx < 32){ W = Wq; Wt = Wqt; N = 1024; n0 = bxx * 32; }
  else         { W = Wo; Wt = Wot; N = 512;  n0 = (bxx - 32) * 32; }
  int k0 = byy * 32;
  int tx = threadIdx.x & 31, ty = threadIdx.x >> 5;   // 32x8
  #pragma unroll
  for (int r = 0; r < 32; r += 8)
    tile[ty + r][tx] = W[(size_t)(k0 + ty + r) * N + n0 + tx];
  __syncthreads();
  #pragma unroll
  for (int r = 0; r < 32; r += 8)
    Wt[(size_t)(n0 + ty + r) * 512 + k0 + tx] = f2bf(tile[tx][ty + r]);
}

// ---------- K1: QKV GEMM, 128x128, 8 waves (2x4), 3-buf depth-2 (R12-proven) ----------
__launch_bounds__(512)
__global__ void k_gemm0(const unsigned short* __restrict__ A,
                        const unsigned short* __restrict__ Bt,
                        const float* __restrict__ bias,
                        unsigned short* __restrict__ qb,
                        unsigned short* __restrict__ kb,
                        unsigned short* __restrict__ vt,
                        float* __restrict__ vsum_p)
{
  const int K = 512;
  constexpr int NWG = 256;
  __shared__ __align__(16) unsigned short lds[3][256 * 64];   // 3 x 32 KB
  int tid = threadIdx.x;
  int wid = tid >> 6, lane = tid & 63;
  int wm = wid >> 2, wn = wid & 3;       // 2 x 4 wave grid
  int lane15 = lane & 15, laneh = lane >> 4;

  int g = blockIdx.x;
  int gwi = (g & 7) * (NWG / 8) + (g >> 3);
  int bm = gwi / 8, bn = gwi % 8;

  f32x4 acc[4][2] = {};

  int srow_off = lane >> 3;           // 0..7
  int spos     = lane & 7;            // 0..7

  auto STAGE = [&](int buf, int kt){
    int k0 = kt * 64;
    #pragma unroll
    for (int c = 0; c < 4; ++c){
      int g2 = wid * 4 + c;           // 0..31: 16 A groups then 16 B groups
      if (g2 < 16){
        int r = g2 * 8 + srow_off;
        int ch = spos ^ (r & 7);
        gl_lds16(A + (size_t)(bm * 128 + r) * K + k0 + ch * 8, &lds[buf][g2 * 512]);
      } else {
        int gb = g2 - 16;
        int r = gb * 8 + srow_off;
        int ch = spos ^ (r & 7);
        gl_lds16(Bt + (size_t)(bn * 128 + r) * K + k0 + ch * 8, &lds[buf][8192 + gb * 512]);
      }
    }
  };

  auto COMPUTE = [&](int buf){
    #pragma unroll
    for (int kh = 0; kh < 2; ++kh){
      int chunk = kh * 4 + laneh;
      bf16x8 af[4], bfv[2];
      #pragma unroll
      for (int mi = 0; mi < 4; ++mi){
        int row = wm * 64 + mi * 16 + lane15;
        af[mi] = *(const bf16x8*)&lds[buf][row * 64 + (chunk ^ (row & 7)) * 8];
      }
      #pragma unroll
      for (int ni = 0; ni < 2; ++ni){
        int row = wn * 32 + ni * 16 + lane15;
        bfv[ni] = *(const bf16x8*)&lds[buf][8192 + row * 64 + (chunk ^ (row & 7)) * 8];
      }
      #pragma unroll
      for (int mi = 0; mi < 4; ++mi)
        #pragma unroll
        for (int ni = 0; ni < 2; ++ni)
          acc[mi][ni] = __builtin_amdgcn_mfma_f32_16x16x32_bf16(af[mi], bfv[ni], acc[mi][ni], 0, 0, 0);
    }
  };

  STAGE(0, 0);
  STAGE(1, 1);
  #pragma unroll
  for (int kt = 0; kt < 8; ++kt){
    if (kt < 6) STAGE((kt + 2) % 3, kt + 2);
    if (kt < 6)       vmwait<8>();
    else if (kt == 6) vmwait<4>();
    else              vmwait<0>();
    __builtin_amdgcn_s_barrier();
    __builtin_amdgcn_sched_barrier(0);
    COMPUTE(kt % 3);
    __builtin_amdgcn_s_barrier();
    __builtin_amdgcn_sched_barrier(0);
  }

  if (bn >= 4){
    // ---- V path: transpose 128x128 tile in LDS, write vt + vsum partials ----
    unsigned short (*tp)[136] = (unsigned short (*)[136])&lds[0][0];  // 34.8 KB
    #pragma unroll
    for (int mi = 0; mi < 4; ++mi)
      #pragma unroll
      for (int ni = 0; ni < 2; ++ni)
        #pragma unroll
        for (int r = 0; r < 4; ++r){
          int ml = wm * 64 + mi * 16 + laneh * 4 + r;
          int nl = wn * 32 + ni * 16 + lane15;
          tp[nl][ml] = f2bf(acc[mi][ni][r] + bias[bn * 128 + nl]);
        }
    __syncthreads();
    int nl = tid >> 2, q = tid & 3;       // nl 0..127, q covers 32 s each
    int h = (bn - 4) * 4 + (nl >> 5), d = nl & 31;
    int b = bm >> 4, sc = bm & 15;        // 128-row s-chunk within batch
    int bh = b * 16 + h;
    uint4 v4[4];
    float ssum = 0.f;
    #pragma unroll
    for (int p = 0; p < 4; ++p){
      v4[p] = *(const uint4*)&tp[nl][q * 32 + p * 8];
      const unsigned* w = (const unsigned*)&v4[p];
      #pragma unroll
      for (int j = 0; j < 4; ++j)
        ssum += bf2f((unsigned short)(w[j] & 0xffff)) + bf2f((unsigned short)(w[j] >> 16));
    }
    ssum += __shfl_xor(ssum, 1); ssum += __shfl_xor(ssum, 2);
    size_t vtoff = (size_t)(bh * HDIM + d) * SEQ + sc * 128 + q * 32;
    #pragma unroll
    for (int p = 0; p < 4; ++p) *(uint4*)(vt + vtoff + p * 8) = v4[p];
    if (q == 0) vsum_p[(sc * 32 + bh) * HDIM + d] = ssum;
  } else {
    #pragma unroll
    for (int mi = 0; mi < 4; ++mi){
      #pragma unroll
      for (int ni = 0; ni < 2; ++ni){
        #pragma unroll
        for (int r = 0; r < 4; ++r){
          int m = bm * 128 + wm * 64 + mi * 16 + laneh * 4 + r;
          int n = bn * 128 + wn * 32 + ni * 16 + lane15;
          float val = acc[mi][ni][r] + bias[n];
          int b = m >> 11, s = m & 2047;
          int h = n >> 5, d = n & 31;
          size_t idx = ((size_t)(b * 16 + h) * SEQ + s) * HDIM + d;
          float sv = val / (1.0f + __expf(-val)) * QSCALE;      // silu * scale
          float tv = 1.0f - 2.0f / (1.0f + __expf(2.0f * val)); // tanh
          qb[idx] = f2bf(sv);
          kb[idx] = f2bf(tv);
        }
      }
    }
  }
}

// ---------- K4: out-proj GEMM, 64x64, 4 waves, 3-buf depth-2 ----------
// A = ao in HEAD-MAJOR [bh][s][32]; K-chunk (kt,ch) lives in head 2kt+(ch>>2)
// at within-head offset (ch&3)*8 -> same single gl_lds16, remapped source.
__launch_bounds__(256)
__global__ void k_gemm1(const unsigned short* __restrict__ ao,
                        const unsigned short* __restrict__ Bt,
                        const float* __restrict__ bias,
                        const unsigned short* __restrict__ xb,
                        unsigned short* __restrict__ yb)
{
  const int K = 512;
  constexpr int NWG = 512;
  __shared__ __align__(16) unsigned short lds[3][128 * 64];
  int tid = threadIdx.x;
  int wid = tid >> 6, lane = tid & 63;
  int wm = wid >> 1, wn = wid & 1;
  int lane15 = lane & 15, laneh = lane >> 4;

  int g = blockIdx.x;
  int gwi = (g & 7) * (NWG / 8) + (g >> 3);
  int bm = gwi / 8, bn = gwi % 8;

  f32x4 acc[2][2] = {};

  int srow_off = lane >> 3;
  int spos     = lane & 7;

  auto STAGE = [&](int buf, int kt){
    int k0 = kt * 64;
    #pragma unroll
    for (int c = 0; c < 2; ++c){
      int cidx = wid * 2 + c;
      int m = bm * 64 + cidx * 8 + srow_off;
      int ch = spos ^ (m & 7);          // bm*64 is 8-aligned: m&7 == rowintile&7
      int head = (kt << 1) + (ch >> 2);
      int b = m >> 11, s = m & 2047;
      gl_lds16(ao + ((size_t)(b * 16 + head) * SEQ + s) * HDIM + (ch & 3) * 8,
               &lds[buf][cidx * 512]);
    }
    #pragma unroll
    for (int c = 0; c < 2; ++c){
      int cidx = wid * 2 + c;
      int r = cidx * 8 + srow_off;
      int ch = spos ^ (r & 7);
      gl_lds16(Bt + (size_t)(bn * 64 + r) * K + k0 + ch * 8, &lds[buf][4096 + cidx * 512]);
    }
  };

  auto COMPUTE = [&](int buf){
    #pragma unroll
    for (int kh = 0; kh < 2; ++kh){
      int chunk = kh * 4 + laneh;
      bf16x8 af[2], bfv[2];
      #pragma unroll
      for (int mi = 0; mi < 2; ++mi){
        int row = wm * 32 + mi * 16 + lane15;
        af[mi] = *(const bf16x8*)&lds[buf][row * 64 + (chunk ^ (row & 7)) * 8];
      }
      #pragma unroll
      for (int ni = 0; ni < 2; ++ni){
        int row = wn * 32 + ni * 16 + lane15;
        bfv[ni] = *(const bf16x8*)&lds[buf][4096 + row * 64 + (chunk ^ (row & 7)) * 8];
      }
      #pragma unroll
      for (int mi = 0; mi < 2; ++mi)
        #pragma unroll
        for (int ni = 0; ni < 2; ++ni)
          acc[mi][ni] = __builtin_amdgcn_mfma_f32_16x16x32_bf16(af[mi], bfv[ni], acc[mi][ni], 0, 0, 0);
    }
  };

  STAGE(0, 0);
  STAGE(1, 1);
  #pragma unroll
  for (int kt = 0; kt < 8; ++kt){
    if (kt < 6) STAGE((kt + 2) % 3, kt + 2);
    if (kt < 6)       vmwait<8>();
    else if (kt == 6) vmwait<4>();
    else              vmwait<0>();
    __builtin_amdgcn_s_barrier();
    __builtin_amdgcn_sched_barrier(0);
    COMPUTE(kt % 3);
    __builtin_amdgcn_s_barrier();
    __builtin_amdgcn_sched_barrier(0);
  }

  #pragma unroll
  for (int mi = 0; mi < 2; ++mi){
    #pragma unroll
    for (int ni = 0; ni < 2; ++ni){
      #pragma unroll
      for (int r = 0; r < 4; ++r){
        int m = bm * 64 + wm * 32 + mi * 16 + laneh * 4 + r;
        int n = bn * 64 + wn * 32 + ni * 16 + lane15;
        float val = acc[mi][ni][r] + bias[n];
        size_t idx = (size_t)m * DIMX + n;
        yb[idx] = f2bf(val + bf2f(xb[idx]));
      }
    }
  }
}

// ---------- K3: banded attention (e^s - 1 trick), MFMA, 9 k-tiles ----------
// q/k head-major [bh][s][32]; ao also head-major [bh][s][32] (full-line writes).
__launch_bounds__(256)
__global__ void k_attn(const unsigned short* __restrict__ qb,
                       const unsigned short* __restrict__ kb,
                       const unsigned short* __restrict__ vt,
                       const float* __restrict__ vsum_p,
                       unsigned short* __restrict__ ao)
{
  __shared__ unsigned short p_lds[4][16][40];   // per-wave P staging, padded
  int tid = threadIdx.x, wid = tid >> 6, lane = tid & 63;
  int lane15 = lane & 15, laneh = lane >> 4;
  int bh = blockIdx.y;
  int s0 = blockIdx.x * 64 + wid * 16;

  bf16x8 qf = *(const bf16x8*)(qb + ((size_t)bh * SEQ + s0 + lane15) * HDIM + laneh * 8);
  float vs0 = 0.f, vs1 = 0.f;
  #pragma unroll
  for (int c = 0; c < 16; ++c){
    vs0 += vsum_p[(c * 32 + bh) * HDIM + lane15];
    vs1 += vsum_p[(c * 32 + bh) * HDIM + 16 + lane15];
  }

  f32x4 accv[2] = {};
  float dsum[4] = {0.f, 0.f, 0.f, 0.f};
  const unsigned short* kbh = kb + (size_t)bh * SEQ * HDIM;
  const unsigned short* vth = vt + (size_t)bh * HDIM * SEQ;

  // band |i-j|<=64 with i in [s0, s0+16) touches j in [s0-64, s0+80) = 9 tiles
  for (int jt = 0; jt < 9; ++jt){
    int j0 = s0 - 64 + jt * 16;
    int jc = min(max(j0 + lane15, 0), SEQ - 1);
    bf16x8 kf = *(const bf16x8*)(kbh + (size_t)jc * HDIM + laneh * 8);
    f32x4 z = {0.f, 0.f, 0.f, 0.f};
    f32x4 sv = __builtin_amdgcn_mfma_f32_16x16x32_bf16(qf, kf, z, 0, 0, 0);
    #pragma unroll
    for (int r = 0; r < 4; ++r){
      int i = s0 + laneh * 4 + r;
      int j = j0 + lane15;
      int dj = i - j;
      bool inb = (dj <= WIN) && (dj >= -WIN) && (j >= 0) && (j < SEQ);
      float w = inb ? (__expf(sv[r]) - 1.0f) : 0.0f;
      dsum[r] += w;
      p_lds[wid][laneh * 4 + r][(jt & 1) * 16 + lane15] = f2bf(w);
    }
    if (jt & 1){
      int jc0 = j0 - 16;   // 32-wide chunk base
      bf16x8 pa = *(const bf16x8*)&p_lds[wid][lane15][laneh * 8];
      int jv = min(max(jc0 + laneh * 8, 0), SEQ - 8);
      bf16x8 v0 = *(const bf16x8*)(vth + (size_t)lane15 * SEQ + jv);
      bf16x8 v1 = *(const bf16x8*)(vth + (size_t)(16 + lane15) * SEQ + jv);
      accv[0] = __builtin_amdgcn_mfma_f32_16x16x32_bf16(pa, v0, accv[0], 0, 0, 0);
      accv[1] = __builtin_amdgcn_mfma_f32_16x16x32_bf16(pa, v1, accv[1], 0, 0, 0);
    }
  }
  // tail PV for tile 8 (cols 0..15); zero cols 16..31 first
  {
    #pragma unroll
    for (int r = 0; r < 4; ++r)
      p_lds[wid][laneh * 4 + r][16 + lane15] = 0;
    int jc0 = s0 + 64;
    bf16x8 pa = *(const bf16x8*)&p_lds[wid][lane15][laneh * 8];
    int jv = min(max(jc0 + laneh * 8, 0), SEQ - 8);
    bf16x8 v0 = *(const bf16x8*)(vth + (size_t)lane15 * SEQ + jv);
    bf16x8 v1 = *(const bf16x8*)(vth + (size_t)(16 + lane15) * SEQ + jv);
    accv[0] = __builtin_amdgcn_mfma_f32_16x16x32_bf16(pa, v0, accv[0], 0, 0, 0);
    accv[1] = __builtin_amdgcn_mfma_f32_16x16x32_bf16(pa, v1, accv[1], 0, 0, 0);
  }

  #pragma unroll
  for (int r = 0; r < 4; ++r){
    float v = dsum[r];
    v += __shfl_xor(v, 1); v += __shfl_xor(v, 2);
    v += __shfl_xor(v, 4); v += __shfl_xor(v, 8);
    dsum[r] = v;
  }
  #pragma unroll
  for (int r = 0; r < 4; ++r){
    int i = s0 + laneh * 4 + r;
    float dn = (float)SEQ + dsum[r];
    float o0 = (accv[0][r] + vs0) / dn;
    float o1 = (accv[1][r] + vs1) / dn;
    size_t base = ((size_t)bh * SEQ + i) * HDIM;   // head-major: full 64B rows
    ao[base + lane15]      = f2bf(o0);
    ao[base + 16 + lane15] = f2bf(o1);
  }
}

// ---------- K5: LayerNorm over 512 (bf16 in, fp32 out), one wave per row ----------
__global__ void k_ln(const unsigned short* __restrict__ yb, const float* __restrict__ gamma,
                     const float* __restrict__ beta, float* __restrict__ out){
  int wid = threadIdx.x >> 6, lane = threadIdx.x & 63;
  int row = blockIdx.x * 4 + wid;
  uint4 u = *(const uint4*)(yb + (size_t)row * DIMX + lane * 8);
  const unsigned* w = (const unsigned*)&u;
  float v[8];
  #pragma unroll
  for (int j = 0; j < 4; ++j){
    v[2*j]   = bf2f((unsigned short)(w[j] & 0xffff));
    v[2*j+1] = bf2f((unsigned short)(w[j] >> 16));
  }
  float s = 0.f, ss = 0.f;
  #pragma unroll
  for (int j = 0; j < 8; ++j){ s += v[j]; ss += v[j] * v[j]; }
  #pragma unroll
  for (int m = 1; m < 64; m <<= 1){ s += __shfl_xor(s, m); ss += __shfl_xor(ss, m); }
  float mu = s * (1.f / DIMX);
  float var = ss * (1.f / DIMX) - mu * mu;
  float inv = rsqrtf(var + 1e-5f);
  float4 g0 = *(const float4*)(gamma + lane * 8);
  float4 g1 = *(const float4*)(gamma + lane * 8 + 4);
  float4 b0 = *(const float4*)(beta + lane * 8);
  float4 b1 = *(const float4*)(beta + lane * 8 + 4);
  float4 o0, o1;
  o0.x = (v[0] - mu) * inv * g0.x + b0.x; o0.y = (v[1] - mu) * inv * g0.y + b0.y;
  o0.z = (v[2] - mu) * inv * g0.z + b0.z; o0.w = (v[3] - mu) * inv * g0.w + b0.w;
  o1.x = (v[4] - mu) * inv * g1.x + b1.x; o1.y = (v[5] - mu) * inv * g1.y + b1.y;
  o1.z = (v[6] - mu) * inv * g1.z + b1.z; o1.w = (v[7] - mu) * inv * g1.w + b1.w;
  float* op = out + (size_t)row * DIMX + lane * 8;
  *(float4*)op = o0; *(float4*)(op + 4) = o1;
}

extern "C" void kernel_launch(void* const* d_in, const int* in_sizes, int n_in,
                              void* d_out, int out_size, void* d_ws, size_t ws_size,
                              hipStream_t stream){
  const float* x      = (const float*)d_in[0];
  const float* W_qkv  = (const float*)d_in[1];
  const float* b_qkv  = (const float*)d_in[2];
  const float* W_out  = (const float*)d_in[3];
  const float* b_out  = (const float*)d_in[4];
  const float* gamma  = (const float*)d_in[5];
  const float* beta   = (const float*)d_in[6];
  float* out = (float*)d_out;

  char* ws = (char*)d_ws;
  size_t off = 0;
  auto alloc = [&](size_t bytes){ void* p = ws + off; off += (bytes + 255) & ~(size_t)255; return p; };
  unsigned short* xb  = (unsigned short*)alloc((size_t)MTOT * DIMX * 2);
  unsigned short* wqt = (unsigned short*)alloc((size_t)1024 * 512 * 2);
  unsigned short* wot = (unsigned short*)alloc((size_t)512 * 512 * 2);
  unsigned short* qb  = (unsigned short*)alloc((size_t)MTOT * DIMX * 2);
  unsigned short* kb  = (unsigned short*)alloc((size_t)MTOT * DIMX * 2);
  unsigned short* vt  = (unsigned short*)alloc((size_t)32 * HDIM * SEQ * 2);
  float*          vsm = (float*)alloc((size_t)16 * 32 * HDIM * 4);
  unsigned short* ao  = (unsigned short*)alloc((size_t)MTOT * DIMX * 2);
  unsigned short* yb  = (unsigned short*)alloc((size_t)MTOT * DIMX * 2);

  k_prep <<<1792, 256, 0, stream>>>(x, xb, W_qkv, wqt, W_out, wot);
  k_gemm0<<<256, 512, 0, stream>>>(xb, wqt, b_qkv, qb, kb, vt, vsm);
  k_attn <<<dim3(32, 32), 256, 0, stream>>>(qb, kb, vt, vsm, ao);
  k_gemm1<<<512, 256, 0, stream>>>(ao, wot, b_out, xb, yb);
  k_ln   <<<MTOT / 4, 256, 0, stream>>>(yb, gamma, beta, out);
}

// Round 18
// 43.140 us; speedup vs baseline: 2.5077x; 1.0168x over previous
//
#include <hip/hip_runtime.h>
#include <cstdint>
#include <cstddef>

#define DIMX 512
#define HDIM 32
#define NHEADS 16
#define SEQ 2048
#define BATCH 2
#define MTOT (BATCH*SEQ)   // 4096
#define WIN 64
#define QSCALE 0.17677669529663687f  // 32^-0.5

typedef __bf16 bf16x8 __attribute__((ext_vector_type(8)));
typedef float f32x4 __attribute__((ext_vector_type(4)));

__device__ __forceinline__ unsigned short f2bf(float f){
  unsigned u = __builtin_bit_cast(unsigned, f);
  u += 0x7FFFu + ((u >> 16) & 1u);          // RNE
  return (unsigned short)(u >> 16);
}
__device__ __forceinline__ float bf2f(unsigned short s){
  return __builtin_bit_cast(float, ((unsigned)s) << 16);
}
__device__ __forceinline__ unsigned pk(float a, float b){
  return (unsigned)f2bf(a) | ((unsigned)f2bf(b) << 16);
}

// async global->LDS, 16B per lane; dest is wave-uniform base + lane*16 (HW)
__device__ __forceinline__ void gl_lds16(const void* g, void* l){
  __builtin_amdgcn_global_load_lds(
      (const __attribute__((address_space(1))) unsigned*)g,
      (__attribute__((address_space(3))) unsigned*)(unsigned)(unsigned long long)l,
      16, 0, 0);
}

template<int N> __device__ __forceinline__ void vmwait(){
  if      constexpr (N == 16) asm volatile("s_waitcnt vmcnt(16)" ::: "memory");
  else if constexpr (N ==  8) asm volatile("s_waitcnt vmcnt(8)"  ::: "memory");
  else if constexpr (N ==  4) asm volatile("s_waitcnt vmcnt(4)"  ::: "memory");
  else                        asm volatile("s_waitcnt vmcnt(0)"  ::: "memory");
}

// ---------- K0: fused x->bf16 convert (blocks 0..1023) + weight transposes ----------
__global__ void k_prep(const float* __restrict__ x, unsigned short* __restrict__ xb,
                       const float* __restrict__ Wq, unsigned short* __restrict__ Wqt,
                       const float* __restrict__ Wo, unsigned short* __restrict__ Wot){
  int bx = blockIdx.x;
  if (bx < 1024){                      // cvt: 8 elems/thread
    int i = bx * 256 + threadIdx.x;
    const float4* p = (const float4*)x + (size_t)i * 2;
    float4 a = p[0], b = p[1];
    uint4 o;
    o.x = pk(a.x, a.y); o.y = pk(a.z, a.w);
    o.z = pk(b.x, b.y); o.w = pk(b.z, b.w);
    ((uint4*)xb)[i] = o;
    return;
  }
  __shared__ float tile[32][33];
  int i = bx - 1024;                   // 0..767 -> (bxx 0..47, byy 0..15)
  int bxx = i % 48, byy = i / 48;
  const float* W; unsigned short* Wt; int N, n0;
  if (bxx < 32){ W = Wq; Wt = Wqt; N = 1024; n0 = bxx * 32; }
  else         { W = Wo; Wt = Wot; N = 512;  n0 = (bxx - 32) * 32; }
  int k0 = byy * 32;
  int tx = threadIdx.x & 31, ty = threadIdx.x >> 5;   // 32x8
  #pragma unroll
  for (int r = 0; r < 32; r += 8)
    tile[ty + r][tx] = W[(size_t)(k0 + ty + r) * N + n0 + tx];
  __syncthreads();
  #pragma unroll
  for (int r = 0; r < 32; r += 8)
    Wt[(size_t)(n0 + ty + r) * 512 + k0 + tx] = f2bf(tile[tx][ty + r]);
}

// ---------- K1: QKV GEMM, 128x128, 8 waves (2x4), 3-buf depth-2 + setprio ----------
__launch_bounds__(512)
__global__ void k_gemm0(const unsigned short* __restrict__ A,
                        const unsigned short* __restrict__ Bt,
                        const float* __restrict__ bias,
                        unsigned short* __restrict__ qb,
                        unsigned short* __restrict__ kb,
                        unsigned short* __restrict__ vt,
                        float* __restrict__ vsum_p)
{
  const int K = 512;
  constexpr int NWG = 256;
  __shared__ __align__(16) unsigned short lds[3][256 * 64];   // 3 x 32 KB
  int tid = threadIdx.x;
  int wid = tid >> 6, lane = tid & 63;
  int wm = wid >> 2, wn = wid & 3;       // 2 x 4 wave grid
  int lane15 = lane & 15, laneh = lane >> 4;

  int g = blockIdx.x;
  int gwi = (g & 7) * (NWG / 8) + (g >> 3);
  int bm = gwi / 8, bn = gwi % 8;

  f32x4 acc[4][2] = {};

  int srow_off = lane >> 3;           // 0..7
  int spos     = lane & 7;            // 0..7

  auto STAGE = [&](int buf, int kt){
    int k0 = kt * 64;
    #pragma unroll
    for (int c = 0; c < 4; ++c){
      int g2 = wid * 4 + c;           // 0..31: 16 A groups then 16 B groups
      if (g2 < 16){
        int r = g2 * 8 + srow_off;
        int ch = spos ^ (r & 7);
        gl_lds16(A + (size_t)(bm * 128 + r) * K + k0 + ch * 8, &lds[buf][g2 * 512]);
      } else {
        int gb = g2 - 16;
        int r = gb * 8 + srow_off;
        int ch = spos ^ (r & 7);
        gl_lds16(Bt + (size_t)(bn * 128 + r) * K + k0 + ch * 8, &lds[buf][8192 + gb * 512]);
      }
    }
  };

  auto COMPUTE = [&](int buf){
    #pragma unroll
    for (int kh = 0; kh < 2; ++kh){
      int chunk = kh * 4 + laneh;
      bf16x8 af[4], bfv[2];
      #pragma unroll
      for (int mi = 0; mi < 4; ++mi){
        int row = wm * 64 + mi * 16 + lane15;
        af[mi] = *(const bf16x8*)&lds[buf][row * 64 + (chunk ^ (row & 7)) * 8];
      }
      #pragma unroll
      for (int ni = 0; ni < 2; ++ni){
        int row = wn * 32 + ni * 16 + lane15;
        bfv[ni] = *(const bf16x8*)&lds[buf][8192 + row * 64 + (chunk ^ (row & 7)) * 8];
      }
      __builtin_amdgcn_s_setprio(1);
      #pragma unroll
      for (int mi = 0; mi < 4; ++mi)
        #pragma unroll
        for (int ni = 0; ni < 2; ++ni)
          acc[mi][ni] = __builtin_amdgcn_mfma_f32_16x16x32_bf16(af[mi], bfv[ni], acc[mi][ni], 0, 0, 0);
      __builtin_amdgcn_s_setprio(0);
    }
  };

  STAGE(0, 0);
  STAGE(1, 1);
  #pragma unroll
  for (int kt = 0; kt < 8; ++kt){
    if (kt < 6) STAGE((kt + 2) % 3, kt + 2);
    if (kt < 6)       vmwait<8>();
    else if (kt == 6) vmwait<4>();
    else              vmwait<0>();
    __builtin_amdgcn_s_barrier();
    __builtin_amdgcn_sched_barrier(0);
    COMPUTE(kt % 3);
    __builtin_amdgcn_s_barrier();
    __builtin_amdgcn_sched_barrier(0);
  }

  if (bn >= 4){
    // ---- V path: transpose 128x128 tile in LDS, write vt + vsum partials ----
    unsigned short (*tp)[136] = (unsigned short (*)[136])&lds[0][0];  // 34.8 KB
    #pragma unroll
    for (int mi = 0; mi < 4; ++mi)
      #pragma unroll
      for (int ni = 0; ni < 2; ++ni)
        #pragma unroll
        for (int r = 0; r < 4; ++r){
          int ml = wm * 64 + mi * 16 + laneh * 4 + r;
          int nl = wn * 32 + ni * 16 + lane15;
          tp[nl][ml] = f2bf(acc[mi][ni][r] + bias[bn * 128 + nl]);
        }
    __syncthreads();
    int nl = tid >> 2, q = tid & 3;       // nl 0..127, q covers 32 s each
    int h = (bn - 4) * 4 + (nl >> 5), d = nl & 31;
    int b = bm >> 4, sc = bm & 15;        // 128-row s-chunk within batch
    int bh = b * 16 + h;
    uint4 v4[4];
    float ssum = 0.f;
    #pragma unroll
    for (int p = 0; p < 4; ++p){
      v4[p] = *(const uint4*)&tp[nl][q * 32 + p * 8];
      const unsigned* w = (const unsigned*)&v4[p];
      #pragma unroll
      for (int j = 0; j < 4; ++j)
        ssum += bf2f((unsigned short)(w[j] & 0xffff)) + bf2f((unsigned short)(w[j] >> 16));
    }
    ssum += __shfl_xor(ssum, 1); ssum += __shfl_xor(ssum, 2);
    size_t vtoff = (size_t)(bh * HDIM + d) * SEQ + sc * 128 + q * 32;
    #pragma unroll
    for (int p = 0; p < 4; ++p) *(uint4*)(vt + vtoff + p * 8) = v4[p];
    if (q == 0) vsum_p[(sc * 32 + bh) * HDIM + d] = ssum;
  } else {
    #pragma unroll
    for (int mi = 0; mi < 4; ++mi){
      #pragma unroll
      for (int ni = 0; ni < 2; ++ni){
        #pragma unroll
        for (int r = 0; r < 4; ++r){
          int m = bm * 128 + wm * 64 + mi * 16 + laneh * 4 + r;
          int n = bn * 128 + wn * 32 + ni * 16 + lane15;
          float val = acc[mi][ni][r] + bias[n];
          int b = m >> 11, s = m & 2047;
          int h = n >> 5, d = n & 31;
          size_t idx = ((size_t)(b * 16 + h) * SEQ + s) * HDIM + d;
          float sv = val / (1.0f + __expf(-val)) * QSCALE;      // silu * scale
          float tv = 1.0f - 2.0f / (1.0f + __expf(2.0f * val)); // tanh
          qb[idx] = f2bf(sv);
          kb[idx] = f2bf(tv);
        }
      }
    }
  }
}

// ---------- K4: out-proj GEMM, 64x64, 4 waves, 3-buf depth-2 + setprio ----------
// A = ao in HEAD-MAJOR [bh][s][32]; K-chunk (kt,ch) lives in head 2kt+(ch>>2)
// at within-head offset (ch&3)*8 -> same single gl_lds16, remapped source.
__launch_bounds__(256)
__global__ void k_gemm1(const unsigned short* __restrict__ ao,
                        const unsigned short* __restrict__ Bt,
                        const float* __restrict__ bias,
                        const unsigned short* __restrict__ xb,
                        unsigned short* __restrict__ yb)
{
  const int K = 512;
  constexpr int NWG = 512;
  __shared__ __align__(16) unsigned short lds[3][128 * 64];
  int tid = threadIdx.x;
  int wid = tid >> 6, lane = tid & 63;
  int wm = wid >> 1, wn = wid & 1;
  int lane15 = lane & 15, laneh = lane >> 4;

  int g = blockIdx.x;
  int gwi = (g & 7) * (NWG / 8) + (g >> 3);
  int bm = gwi / 8, bn = gwi % 8;

  f32x4 acc[2][2] = {};

  int srow_off = lane >> 3;
  int spos     = lane & 7;

  auto STAGE = [&](int buf, int kt){
    int k0 = kt * 64;
    #pragma unroll
    for (int c = 0; c < 2; ++c){
      int cidx = wid * 2 + c;
      int m = bm * 64 + cidx * 8 + srow_off;
      int ch = spos ^ (m & 7);          // bm*64 is 8-aligned: m&7 == rowintile&7
      int head = (kt << 1) + (ch >> 2);
      int b = m >> 11, s = m & 2047;
      gl_lds16(ao + ((size_t)(b * 16 + head) * SEQ + s) * HDIM + (ch & 3) * 8,
               &lds[buf][cidx * 512]);
    }
    #pragma unroll
    for (int c = 0; c < 2; ++c){
      int cidx = wid * 2 + c;
      int r = cidx * 8 + srow_off;
      int ch = spos ^ (r & 7);
      gl_lds16(Bt + (size_t)(bn * 64 + r) * K + k0 + ch * 8, &lds[buf][4096 + cidx * 512]);
    }
  };

  auto COMPUTE = [&](int buf){
    #pragma unroll
    for (int kh = 0; kh < 2; ++kh){
      int chunk = kh * 4 + laneh;
      bf16x8 af[2], bfv[2];
      #pragma unroll
      for (int mi = 0; mi < 2; ++mi){
        int row = wm * 32 + mi * 16 + lane15;
        af[mi] = *(const bf16x8*)&lds[buf][row * 64 + (chunk ^ (row & 7)) * 8];
      }
      #pragma unroll
      for (int ni = 0; ni < 2; ++ni){
        int row = wn * 32 + ni * 16 + lane15;
        bfv[ni] = *(const bf16x8*)&lds[buf][4096 + row * 64 + (chunk ^ (row & 7)) * 8];
      }
      __builtin_amdgcn_s_setprio(1);
      #pragma unroll
      for (int mi = 0; mi < 2; ++mi)
        #pragma unroll
        for (int ni = 0; ni < 2; ++ni)
          acc[mi][ni] = __builtin_amdgcn_mfma_f32_16x16x32_bf16(af[mi], bfv[ni], acc[mi][ni], 0, 0, 0);
      __builtin_amdgcn_s_setprio(0);
    }
  };

  STAGE(0, 0);
  STAGE(1, 1);
  #pragma unroll
  for (int kt = 0; kt < 8; ++kt){
    if (kt < 6) STAGE((kt + 2) % 3, kt + 2);
    if (kt < 6)       vmwait<8>();
    else if (kt == 6) vmwait<4>();
    else              vmwait<0>();
    __builtin_amdgcn_s_barrier();
    __builtin_amdgcn_sched_barrier(0);
    COMPUTE(kt % 3);
    __builtin_amdgcn_s_barrier();
    __builtin_amdgcn_sched_barrier(0);
  }

  #pragma unroll
  for (int mi = 0; mi < 2; ++mi){
    #pragma unroll
    for (int ni = 0; ni < 2; ++ni){
      #pragma unroll
      for (int r = 0; r < 4; ++r){
        int m = bm * 64 + wm * 32 + mi * 16 + laneh * 4 + r;
        int n = bn * 64 + wn * 32 + ni * 16 + lane15;
        float val = acc[mi][ni][r] + bias[n];
        size_t idx = (size_t)m * DIMX + n;
        yb[idx] = f2bf(val + bf2f(xb[idx]));
      }
    }
  }
}

// ---------- K3: banded attention (e^s - 1 trick), MFMA, 9 k-tiles + setprio ----------
// q/k head-major [bh][s][32]; ao also head-major [bh][s][32] (full-line writes).
__launch_bounds__(256)
__global__ void k_attn(const unsigned short* __restrict__ qb,
                       const unsigned short* __restrict__ kb,
                       const unsigned short* __restrict__ vt,
                       const float* __restrict__ vsum_p,
                       unsigned short* __restrict__ ao)
{
  __shared__ unsigned short p_lds[4][16][40];   // per-wave P staging, padded
  int tid = threadIdx.x, wid = tid >> 6, lane = tid & 63;
  int lane15 = lane & 15, laneh = lane >> 4;
  int bh = blockIdx.y;
  int s0 = blockIdx.x * 64 + wid * 16;

  bf16x8 qf = *(const bf16x8*)(qb + ((size_t)bh * SEQ + s0 + lane15) * HDIM + laneh * 8);
  float vs0 = 0.f, vs1 = 0.f;
  #pragma unroll
  for (int c = 0; c < 16; ++c){
    vs0 += vsum_p[(c * 32 + bh) * HDIM + lane15];
    vs1 += vsum_p[(c * 32 + bh) * HDIM + 16 + lane15];
  }

  f32x4 accv[2] = {};
  float dsum[4] = {0.f, 0.f, 0.f, 0.f};
  const unsigned short* kbh = kb + (size_t)bh * SEQ * HDIM;
  const unsigned short* vth = vt + (size_t)bh * HDIM * SEQ;

  // band |i-j|<=64 with i in [s0, s0+16) touches j in [s0-64, s0+80) = 9 tiles
  for (int jt = 0; jt < 9; ++jt){
    int j0 = s0 - 64 + jt * 16;
    int jc = min(max(j0 + lane15, 0), SEQ - 1);
    bf16x8 kf = *(const bf16x8*)(kbh + (size_t)jc * HDIM + laneh * 8);
    f32x4 z = {0.f, 0.f, 0.f, 0.f};
    __builtin_amdgcn_s_setprio(1);
    f32x4 sv = __builtin_amdgcn_mfma_f32_16x16x32_bf16(qf, kf, z, 0, 0, 0);
    __builtin_amdgcn_s_setprio(0);
    #pragma unroll
    for (int r = 0; r < 4; ++r){
      int i = s0 + laneh * 4 + r;
      int j = j0 + lane15;
      int dj = i - j;
      bool inb = (dj <= WIN) && (dj >= -WIN) && (j >= 0) && (j < SEQ);
      float w = inb ? (__expf(sv[r]) - 1.0f) : 0.0f;
      dsum[r] += w;
      p_lds[wid][laneh * 4 + r][(jt & 1) * 16 + lane15] = f2bf(w);
    }
    if (jt & 1){
      int jc0 = j0 - 16;   // 32-wide chunk base
      bf16x8 pa = *(const bf16x8*)&p_lds[wid][lane15][laneh * 8];
      int jv = min(max(jc0 + laneh * 8, 0), SEQ - 8);
      bf16x8 v0 = *(const bf16x8*)(vth + (size_t)lane15 * SEQ + jv);
      bf16x8 v1 = *(const bf16x8*)(vth + (size_t)(16 + lane15) * SEQ + jv);
      __builtin_amdgcn_s_setprio(1);
      accv[0] = __builtin_amdgcn_mfma_f32_16x16x32_bf16(pa, v0, accv[0], 0, 0, 0);
      accv[1] = __builtin_amdgcn_mfma_f32_16x16x32_bf16(pa, v1, accv[1], 0, 0, 0);
      __builtin_amdgcn_s_setprio(0);
    }
  }
  // tail PV for tile 8 (cols 0..15); zero cols 16..31 first
  {
    #pragma unroll
    for (int r = 0; r < 4; ++r)
      p_lds[wid][laneh * 4 + r][16 + lane15] = 0;
    int jc0 = s0 + 64;
    bf16x8 pa = *(const bf16x8*)&p_lds[wid][lane15][laneh * 8];
    int jv = min(max(jc0 + laneh * 8, 0), SEQ - 8);
    bf16x8 v0 = *(const bf16x8*)(vth + (size_t)lane15 * SEQ + jv);
    bf16x8 v1 = *(const bf16x8*)(vth + (size_t)(16 + lane15) * SEQ + jv);
    __builtin_amdgcn_s_setprio(1);
    accv[0] = __builtin_amdgcn_mfma_f32_16x16x32_bf16(pa, v0, accv[0], 0, 0, 0);
    accv[1] = __builtin_amdgcn_mfma_f32_16x16x32_bf16(pa, v1, accv[1], 0, 0, 0);
    __builtin_amdgcn_s_setprio(0);
  }

  #pragma unroll
  for (int r = 0; r < 4; ++r){
    float v = dsum[r];
    v += __shfl_xor(v, 1); v += __shfl_xor(v, 2);
    v += __shfl_xor(v, 4); v += __shfl_xor(v, 8);
    dsum[r] = v;
  }
  #pragma unroll
  for (int r = 0; r < 4; ++r){
    int i = s0 + laneh * 4 + r;
    float dn = (float)SEQ + dsum[r];
    float o0 = (accv[0][r] + vs0) / dn;
    float o1 = (accv[1][r] + vs1) / dn;
    size_t base = ((size_t)bh * SEQ + i) * HDIM;   // head-major: full 64B rows
    ao[base + lane15]      = f2bf(o0);
    ao[base + 16 + lane15] = f2bf(o1);
  }
}

// ---------- K5: LayerNorm over 512 (bf16 in, fp32 out), one wave per row ----------
__global__ void k_ln(const unsigned short* __restrict__ yb, const float* __restrict__ gamma,
                     const float* __restrict__ beta, float* __restrict__ out){
  int wid = threadIdx.x >> 6, lane = threadIdx.x & 63;
  int row = blockIdx.x * 4 + wid;
  uint4 u = *(const uint4*)(yb + (size_t)row * DIMX + lane * 8);
  const unsigned* w = (const unsigned*)&u;
  float v[8];
  #pragma unroll
  for (int j = 0; j < 4; ++j){
    v[2*j]   = bf2f((unsigned short)(w[j] & 0xffff));
    v[2*j+1] = bf2f((unsigned short)(w[j] >> 16));
  }
  float s = 0.f, ss = 0.f;
  #pragma unroll
  for (int j = 0; j < 8; ++j){ s += v[j]; ss += v[j] * v[j]; }
  #pragma unroll
  for (int m = 1; m < 64; m <<= 1){ s += __shfl_xor(s, m); ss += __shfl_xor(ss, m); }
  float mu = s * (1.f / DIMX);
  float var = ss * (1.f / DIMX) - mu * mu;
  float inv = rsqrtf(var + 1e-5f);
  float4 g0 = *(const float4*)(gamma + lane * 8);
  float4 g1 = *(const float4*)(gamma + lane * 8 + 4);
  float4 b0 = *(const float4*)(beta + lane * 8);
  float4 b1 = *(const float4*)(beta + lane * 8 + 4);
  float4 o0, o1;
  o0.x = (v[0] - mu) * inv * g0.x + b0.x; o0.y = (v[1] - mu) * inv * g0.y + b0.y;
  o0.z = (v[2] - mu) * inv * g0.z + b0.z; o0.w = (v[3] - mu) * inv * g0.w + b0.w;
  o1.x = (v[4] - mu) * inv * g1.x + b1.x; o1.y = (v[5] - mu) * inv * g1.y + b1.y;
  o1.z = (v[6] - mu) * inv * g1.z + b1.z; o1.w = (v[7] - mu) * inv * g1.w + b1.w;
  float* op = out + (size_t)row * DIMX + lane * 8;
  *(float4*)op = o0; *(float4*)(op + 4) = o1;
}

extern "C" void kernel_launch(void* const* d_in, const int* in_sizes, int n_in,
                              void* d_out, int out_size, void* d_ws, size_t ws_size,
                              hipStream_t stream){
  const float* x      = (const float*)d_in[0];
  const float* W_qkv  = (const float*)d_in[1];
  const float* b_qkv  = (const float*)d_in[2];
  const float* W_out  = (const float*)d_in[3];
  const float* b_out  = (const float*)d_in[4];
  const float* gamma  = (const float*)d_in[5];
  const float* beta   = (const float*)d_in[6];
  float* out = (float*)d_out;

  char* ws = (char*)d_ws;
  size_t off = 0;
  auto alloc = [&](size_t bytes){ void* p = ws + off; off += (bytes + 255) & ~(size_t)255; return p; };
  unsigned short* xb  = (unsigned short*)alloc((size_t)MTOT * DIMX * 2);
  unsigned short* wqt = (unsigned short*)alloc((size_t)1024 * 512 * 2);
  unsigned short* wot = (unsigned short*)alloc((size_t)512 * 512 * 2);
  unsigned short* qb  = (unsigned short*)alloc((size_t)MTOT * DIMX * 2);
  unsigned short* kb  = (unsigned short*)alloc((size_t)MTOT * DIMX * 2);
  unsigned short* vt  = (unsigned short*)alloc((size_t)32 * HDIM * SEQ * 2);
  float*          vsm = (float*)alloc((size_t)16 * 32 * HDIM * 4);
  unsigned short* ao  = (unsigned short*)alloc((size_t)MTOT * DIMX * 2);
  unsigned short* yb  = (unsigned short*)alloc((size_t)MTOT * DIMX * 2);

  k_prep <<<1792, 256, 0, stream>>>(x, xb, W_qkv, wqt, W_out, wot);
  k_gemm0<<<256, 512, 0, stream>>>(xb, wqt, b_qkv, qb, kb, vt, vsm);
  k_attn <<<dim3(32, 32), 256, 0, stream>>>(qb, kb, vt, vsm, ao);
  k_gemm1<<<512, 256, 0, stream>>>(ao, wot, b_out, xb, yb);
  k_ln   <<<MTOT / 4, 256, 0, stream>>>(yb, gamma, beta, out);
}